// Round 10
// baseline (240.375 us; speedup 1.0000x reference)
//
#include <hip/hip_runtime.h>
#include <hip/hip_bf16.h>

typedef short short8 __attribute__((ext_vector_type(8)));   // 8 bf16 = 4 VGPRs
typedef float f32x4 __attribute__((ext_vector_type(4)));
typedef unsigned short u16;

__device__ __forceinline__ unsigned short f2bf(float f) {
  unsigned int u = __float_as_uint(f);
  u += 0x7fffu + ((u >> 16) & 1u);    // round-to-nearest-even
  return (unsigned short)(u >> 16);
}

// async 16B global->LDS (dest = wave-uniform base + lane*16)
__device__ __forceinline__ void glds16(const void* g, void* l) {
  __builtin_amdgcn_global_load_lds(
      (const __attribute__((address_space(1))) unsigned int*)g,
      (__attribute__((address_space(3))) unsigned int*)l, 16, 0, 0);
}

// Explicit full drain (vmcnt=0, expcnt=0, lgkmcnt=0) BEFORE s_barrier.
// __syncthreads alone is NOT a reliable fence for global_load_lds staging
// (r4-r7 flakiness; r8/r9 passed with this). Makes 1-barrier dbuf race-free.
__device__ __forceinline__ void drain_then_sync() {
  __builtin_amdgcn_s_waitcnt(0);
  __syncthreads();
}

// ---- fused: cast q/m -> bf16, cast wq*(1/(8 ln2)) -> bf16, cast wk, zero out ----
__global__ __launch_bounds__(256) void prep(const float4* __restrict__ q,
                                            const float4* __restrict__ m,
                                            const float4* __restrict__ wq,
                                            const float4* __restrict__ wk,
                                            ushort4* __restrict__ qb,
                                            ushort4* __restrict__ mb,
                                            ushort4* __restrict__ wqb,
                                            ushort4* __restrict__ wkb,
                                            float4* __restrict__ out0) {
  const int i = blockIdx.x * 256 + threadIdx.x;
  const float c = 0.18033688011112042f;  // 1/(8*ln2): folds SCALE and exp->exp2
  if (i < 1048576) {
    float4 v = q[i];
    ushort4 o; o.x = f2bf(v.x); o.y = f2bf(v.y); o.z = f2bf(v.z); o.w = f2bf(v.w);
    qb[i] = o;
  } else if (i < 2097152) {
    float4 v = m[i - 1048576];
    ushort4 o; o.x = f2bf(v.x); o.y = f2bf(v.y); o.z = f2bf(v.z); o.w = f2bf(v.w);
    mb[i - 1048576] = o;
  } else if (i < 2359296) {
    float4 v = wq[i - 2097152];
    ushort4 o; o.x = f2bf(v.x * c); o.y = f2bf(v.y * c); o.z = f2bf(v.z * c); o.w = f2bf(v.w * c);
    wqb[i - 2097152] = o;
  } else if (i < 2621440) {
    float4 v = wk[i - 2359296];
    ushort4 o; o.x = f2bf(v.x); o.y = f2bf(v.y); o.z = f2bf(v.z); o.w = f2bf(v.w);
    wkb[i - 2359296] = o;
  } else if (i < 2637824) {
    out0[i - 2621440] = (float4){0.f, 0.f, 0.f, 0.f};  // zero 65536-float output
  }
}

// ---- C = A[M,1024] @ B[N,1024]^T, 128x128 tile, BK=64, 512 thr (8 waves),
// dbuf LDS, one drain+barrier/iter (r9 PASSING kernel, verbatim). ----
__global__ __launch_bounds__(512) void gemm_db(const u16* __restrict__ A0,
                                               const u16* __restrict__ B0,
                                               u16* __restrict__ C0,
                                               const u16* __restrict__ A1,
                                               const u16* __restrict__ B1,
                                               u16* __restrict__ C1) {
  __shared__ u16 As[2][128 * 64];   // 32 KB
  __shared__ u16 Bs[2][128 * 64];   // 32 KB
  const int zz = blockIdx.x & 1;
  const u16* A = zz ? A1 : A0;
  const u16* B = zz ? B1 : B0;
  u16* C = zz ? C1 : C0;
  const int t = threadIdx.x;
  const int lane = t & 63, wave = t >> 6;     // 8 waves
  const int l15 = lane & 15, quad = lane >> 4;
  const int mb = (blockIdx.x >> 1) * 128;     // M-block (32 of them)
  const int nb = blockIdx.y * 128;            // N-block (8 of them)
  const int wm = (wave & 1) * 64;             // M: 2 x 64
  const int wn = (wave >> 1) * 32;            // N: 4 x 32

  const int srow = lane >> 3;                 // 0..7 row within 8-row group
  const int scol = ((lane & 7) ^ srow) * 8;   // xor-swizzled source column
  const int sw = l15 & 7;

  f32x4 acc[4][2];
#pragma unroll
  for (int i = 0; i < 4; i++)
#pragma unroll
    for (int j = 0; j < 2; j++) acc[i][j] = (f32x4){0.f, 0.f, 0.f, 0.f};

  // prologue: stage kb=0 into buffer 0 (2 A-groups + 2 B-groups per thread)
#pragma unroll
  for (int j = 0; j < 2; j++) {
    const int g = wave * 2 + j;               // 0..15 (8 rows each)
    glds16(A + (size_t)(mb + g * 8 + srow) * 1024 + scol, &As[0][g * 512 + lane * 8]);
    glds16(B + (size_t)(nb + g * 8 + srow) * 1024 + scol, &Bs[0][g * 512 + lane * 8]);
  }

  for (int it = 0; it < 16; ++it) {
    drain_then_sync();  // my buf[it] fills landed; all waves' buf[it^1] reads retired
    if (it < 15) {
      const int kb = (it + 1) * 64, bf_ = (it + 1) & 1;
#pragma unroll
      for (int j = 0; j < 2; j++) {
        const int g = wave * 2 + j;
        glds16(A + (size_t)(mb + g * 8 + srow) * 1024 + kb + scol, &As[bf_][g * 512 + lane * 8]);
        glds16(B + (size_t)(nb + g * 8 + srow) * 1024 + kb + scol, &Bs[bf_][g * 512 + lane * 8]);
      }
    }
    const u16* as = As[it & 1];
    const u16* bs = Bs[it & 1];
#pragma unroll
    for (int kk = 0; kk < 2; kk++) {
      const int cb = kk * 4;
      short8 af[4], bfr[2];
#pragma unroll
      for (int mi = 0; mi < 4; mi++)
        af[mi] = *(const short8*)&as[(wm + mi * 16 + l15) * 64 + ((cb + quad) ^ sw) * 8];
#pragma unroll
      for (int ni = 0; ni < 2; ni++)
        bfr[ni] = *(const short8*)&bs[(wn + ni * 16 + l15) * 64 + ((cb + quad) ^ sw) * 8];
#pragma unroll
      for (int mi = 0; mi < 4; mi++)
#pragma unroll
        for (int ni = 0; ni < 2; ni++)
          acc[mi][ni] = __builtin_amdgcn_mfma_f32_16x16x32_bf16(
              af[mi], bfr[ni], acc[mi][ni], 0, 0, 0);
    }
  }

  // epilogue: C/D layout col=l15, row=quad*4+r (r2-verified)
#pragma unroll
  for (int mi = 0; mi < 4; mi++)
#pragma unroll
    for (int r = 0; r < 4; r++) {
      const int row = mb + wm + mi * 16 + quad * 4 + r;
      const size_t base = (size_t)row * 1024 + nb + wn;
#pragma unroll
      for (int ni = 0; ni < 2; ni++)
        C[base + ni * 16 + l15] = f2bf(acc[mi][ni][r]);
    }
}

// ---- fused QK^T + columnwise LSE, atomicAdd combine over a ----
// Each wave owns 128 k-cols (8 k-tile K-frags in regs); block covers all 512 k
// for one (aa,h,b). 128-row Q tiles, dbuf, 4 barriers/block. z4-as-C kills
// acc-init movs. Q' pre-scaled by 1/(8 ln2): raw v_exp_f32.
__global__ __launch_bounds__(256, 4) void attn_lse4(const u16* __restrict__ Qp,
                                                    const u16* __restrict__ Kp,
                                                    float* __restrict__ out) {
  __shared__ u16 qs[2][128 * 64];   // 32 KB double-buffered
  const int t = threadIdx.x;
  const int lane = t & 63, wave = t >> 6;
  const int l15 = lane & 15, quad = lane >> 4;
  const int aa = blockIdx.x, h = blockIdx.y, b = blockIdx.z;
  const int kbase = wave * 128;

  // K fragments for 8 k-tiles x (d-lo, d-hi), in registers throughout (64 VGPRs)
  short8 klo[8], khi[8];
#pragma unroll
  for (int tt = 0; tt < 8; tt++) {
    const short8* kg = (const short8*)(Kp + (size_t)(b * 512 + kbase + tt * 16 + l15) * 1024
                                       + h * 64 + quad * 8);
    klo[tt] = kg[0];
    khi[tt] = kg[4];   // +32 elements
  }

  const int srow = lane >> 3;
  const int scol = ((lane & 7) ^ srow) * 8;
  const u16* qbase = Qp + (size_t)(aa * 512) * 1024 + h * 64;

  // loop-invariant swizzled LDS read columns (in u16 elements)
  const int sw = l15 & 7;
  const int colLo = (quad ^ sw) * 8;
  const int colHi = ((4 + quad) ^ sw) * 8;
  const int rrow = l15 * 64;

  const f32x4 z4 = (f32x4){0.f, 0.f, 0.f, 0.f};   // persistent zero C operand
  float cs0 = 0.f, cs1 = 0.f, cs2 = 0.f, cs3 = 0.f;
  float cs4 = 0.f, cs5 = 0.f, cs6 = 0.f, cs7 = 0.f;

  // prologue: stage tile 0 (128 q-rows; 16 groups of 8 rows, 4 per wave)
#pragma unroll
  for (int j = 0; j < 4; j++) {
    const int g = wave * 4 + j;
    glds16(qbase + (size_t)(g * 8 + srow) * 1024 + scol, &qs[0][g * 512 + lane * 8]);
  }

  for (int i = 0; i < 4; i++) {
    drain_then_sync();   // my tile-i fills landed; all tile-(i-1) reads retired
    if (i < 3) {
#pragma unroll
      for (int j = 0; j < 4; j++) {
        const int g = wave * 4 + j;
        glds16(qbase + (size_t)((i + 1) * 128 + g * 8 + srow) * 1024 + scol,
               &qs[(i + 1) & 1][g * 512 + lane * 8]);
      }
    }
    const u16* buf = qs[i & 1];
#pragma unroll
    for (int qt = 0; qt < 8; qt++) {
      short8 alo = *(const short8*)&buf[qt * 1024 + rrow + colLo];
      short8 ahi = *(const short8*)&buf[qt * 1024 + rrow + colHi];
      f32x4 a0 = __builtin_amdgcn_mfma_f32_16x16x32_bf16(
          ahi, khi[0], __builtin_amdgcn_mfma_f32_16x16x32_bf16(alo, klo[0], z4, 0, 0, 0), 0, 0, 0);
      f32x4 a1 = __builtin_amdgcn_mfma_f32_16x16x32_bf16(
          ahi, khi[1], __builtin_amdgcn_mfma_f32_16x16x32_bf16(alo, klo[1], z4, 0, 0, 0), 0, 0, 0);
      f32x4 a2 = __builtin_amdgcn_mfma_f32_16x16x32_bf16(
          ahi, khi[2], __builtin_amdgcn_mfma_f32_16x16x32_bf16(alo, klo[2], z4, 0, 0, 0), 0, 0, 0);
      f32x4 a3 = __builtin_amdgcn_mfma_f32_16x16x32_bf16(
          ahi, khi[3], __builtin_amdgcn_mfma_f32_16x16x32_bf16(alo, klo[3], z4, 0, 0, 0), 0, 0, 0);
      f32x4 a4 = __builtin_amdgcn_mfma_f32_16x16x32_bf16(
          ahi, khi[4], __builtin_amdgcn_mfma_f32_16x16x32_bf16(alo, klo[4], z4, 0, 0, 0), 0, 0, 0);
      f32x4 a5 = __builtin_amdgcn_mfma_f32_16x16x32_bf16(
          ahi, khi[5], __builtin_amdgcn_mfma_f32_16x16x32_bf16(alo, klo[5], z4, 0, 0, 0), 0, 0, 0);
      f32x4 a6 = __builtin_amdgcn_mfma_f32_16x16x32_bf16(
          ahi, khi[6], __builtin_amdgcn_mfma_f32_16x16x32_bf16(alo, klo[6], z4, 0, 0, 0), 0, 0, 0);
      f32x4 a7 = __builtin_amdgcn_mfma_f32_16x16x32_bf16(
          ahi, khi[7], __builtin_amdgcn_mfma_f32_16x16x32_bf16(alo, klo[7], z4, 0, 0, 0), 0, 0, 0);
#pragma unroll
      for (int r = 0; r < 4; r++) {
        cs0 += __builtin_amdgcn_exp2f(a0[r]);
        cs1 += __builtin_amdgcn_exp2f(a1[r]);
        cs2 += __builtin_amdgcn_exp2f(a2[r]);
        cs3 += __builtin_amdgcn_exp2f(a3[r]);
        cs4 += __builtin_amdgcn_exp2f(a4[r]);
        cs5 += __builtin_amdgcn_exp2f(a5[r]);
        cs6 += __builtin_amdgcn_exp2f(a6[r]);
        cs7 += __builtin_amdgcn_exp2f(a7[r]);
      }
    }
  }
  // finish column sums over the 4 quads (rows) for each k-tile
  cs0 += __shfl_xor(cs0, 16); cs0 += __shfl_xor(cs0, 32);
  cs1 += __shfl_xor(cs1, 16); cs1 += __shfl_xor(cs1, 32);
  cs2 += __shfl_xor(cs2, 16); cs2 += __shfl_xor(cs2, 32);
  cs3 += __shfl_xor(cs3, 16); cs3 += __shfl_xor(cs3, 32);
  cs4 += __shfl_xor(cs4, 16); cs4 += __shfl_xor(cs4, 32);
  cs5 += __shfl_xor(cs5, 16); cs5 += __shfl_xor(cs5, 32);
  cs6 += __shfl_xor(cs6, 16); cs6 += __shfl_xor(cs6, 32);
  cs7 += __shfl_xor(cs7, 16); cs7 += __shfl_xor(cs7, 32);
  // quad q stores k-tiles 2q and 2q+1
  const float va = quad == 0 ? cs0 : quad == 1 ? cs2 : quad == 2 ? cs4 : cs6;
  const float vb = quad == 0 ? cs1 : quad == 1 ? cs3 : quad == 2 ? cs5 : cs7;
  float* obase = out + (size_t)b * 8192 + h * 512 + kbase;
  atomicAdd(obase + (quad * 2) * 16 + l15, __logf(va));
  atomicAdd(obase + (quad * 2 + 1) * 16 + l15, __logf(vb));
}

extern "C" void kernel_launch(void* const* d_in, const int* in_sizes, int n_in,
                              void* d_out, int out_size, void* d_ws, size_t ws_size,
                              hipStream_t stream) {
  const float* query  = (const float*)d_in[0];  // [8,512,1024]
  const float* memory = (const float*)d_in[1];  // [8,512,1024]
  const float* wq     = (const float*)d_in[2];  // [1024,1024]
  const float* wk     = (const float*)d_in[3];  // [1024,1024]
  float* out = (float*)d_out;                   // [8,16,512]

  char* ws = (char*)d_ws;
  const size_t MB = 1024 * 1024;
  u16* qb  = (u16*)(ws);             // 8 MB bf16 query
  u16* mb_ = (u16*)(ws + 8  * MB);   // 8 MB bf16 memory
  u16* wqb = (u16*)(ws + 16 * MB);   // 2 MB bf16 W_Q * c
  u16* wkb = (u16*)(ws + 18 * MB);   // 2 MB bf16 W_K
  u16* Qp  = (u16*)(ws + 20 * MB);   // 8 MB projected Q'
  u16* Kp  = (u16*)(ws + 28 * MB);   // 8 MB projected K

  prep<<<10304, 256, 0, stream>>>((const float4*)query, (const float4*)memory,
                                  (const float4*)wq, (const float4*)wk,
                                  (ushort4*)qb, (ushort4*)mb_, (ushort4*)wqb,
                                  (ushort4*)wkb, (float4*)d_out);
  gemm_db<<<dim3(64, 8), 512, 0, stream>>>(qb, wqb, Qp, mb_, wkb, Kp);
  attn_lse4<<<dim3(8, 16, 8), 256, 0, stream>>>(Qp, Kp, out);
}

// Round 11
// 147.686 us; speedup vs baseline: 1.6276x; 1.6276x over previous
//
#include <hip/hip_runtime.h>
#include <hip/hip_bf16.h>

typedef short short8 __attribute__((ext_vector_type(8)));   // 8 bf16 = 4 VGPRs
typedef float f32x4 __attribute__((ext_vector_type(4)));
typedef unsigned short u16;

__device__ __forceinline__ unsigned short f2bf(float f) {
  unsigned int u = __float_as_uint(f);
  u += 0x7fffu + ((u >> 16) & 1u);    // round-to-nearest-even
  return (unsigned short)(u >> 16);
}

// async 16B global->LDS (dest = wave-uniform base + lane*16)
__device__ __forceinline__ void glds16(const void* g, void* l) {
  __builtin_amdgcn_global_load_lds(
      (const __attribute__((address_space(1))) unsigned int*)g,
      (__attribute__((address_space(3))) unsigned int*)l, 16, 0, 0);
}

// Explicit full drain (vmcnt=0, expcnt=0, lgkmcnt=0) BEFORE s_barrier.
// __syncthreads alone is NOT a reliable fence for global_load_lds staging
// (r4-r7 flakiness; r8/r9 passed with this). Makes 1-barrier dbuf race-free.
__device__ __forceinline__ void drain_then_sync() {
  __builtin_amdgcn_s_waitcnt(0);
  __syncthreads();
}

// ---- fused: cast q/m -> bf16, cast wq*(1/(8 ln2)) -> bf16, cast wk, zero out ----
__global__ __launch_bounds__(256) void prep(const float4* __restrict__ q,
                                            const float4* __restrict__ m,
                                            const float4* __restrict__ wq,
                                            const float4* __restrict__ wk,
                                            ushort4* __restrict__ qb,
                                            ushort4* __restrict__ mb,
                                            ushort4* __restrict__ wqb,
                                            ushort4* __restrict__ wkb,
                                            float4* __restrict__ out0) {
  const int i = blockIdx.x * 256 + threadIdx.x;
  const float c = 0.18033688011112042f;  // 1/(8*ln2): folds SCALE and exp->exp2
  if (i < 1048576) {
    float4 v = q[i];
    ushort4 o; o.x = f2bf(v.x); o.y = f2bf(v.y); o.z = f2bf(v.z); o.w = f2bf(v.w);
    qb[i] = o;
  } else if (i < 2097152) {
    float4 v = m[i - 1048576];
    ushort4 o; o.x = f2bf(v.x); o.y = f2bf(v.y); o.z = f2bf(v.z); o.w = f2bf(v.w);
    mb[i - 1048576] = o;
  } else if (i < 2359296) {
    float4 v = wq[i - 2097152];
    ushort4 o; o.x = f2bf(v.x * c); o.y = f2bf(v.y * c); o.z = f2bf(v.z * c); o.w = f2bf(v.w * c);
    wqb[i - 2097152] = o;
  } else if (i < 2621440) {
    float4 v = wk[i - 2359296];
    ushort4 o; o.x = f2bf(v.x); o.y = f2bf(v.y); o.z = f2bf(v.z); o.w = f2bf(v.w);
    wkb[i - 2359296] = o;
  } else if (i < 2637824) {
    out0[i - 2621440] = (float4){0.f, 0.f, 0.f, 0.f};  // zero 65536-float output
  }
}

// ---- C = A[M,1024] @ B[N,1024]^T, 128x128 tile, BK=64, 512 thr (8 waves),
// dbuf LDS, one drain+barrier/iter (r9 PASSING kernel, verbatim). ----
__global__ __launch_bounds__(512) void gemm_db(const u16* __restrict__ A0,
                                               const u16* __restrict__ B0,
                                               u16* __restrict__ C0,
                                               const u16* __restrict__ A1,
                                               const u16* __restrict__ B1,
                                               u16* __restrict__ C1) {
  __shared__ u16 As[2][128 * 64];   // 32 KB
  __shared__ u16 Bs[2][128 * 64];   // 32 KB
  const int zz = blockIdx.x & 1;
  const u16* A = zz ? A1 : A0;
  const u16* B = zz ? B1 : B0;
  u16* C = zz ? C1 : C0;
  const int t = threadIdx.x;
  const int lane = t & 63, wave = t >> 6;     // 8 waves
  const int l15 = lane & 15, quad = lane >> 4;
  const int mb = (blockIdx.x >> 1) * 128;     // M-block (32 of them)
  const int nb = blockIdx.y * 128;            // N-block (8 of them)
  const int wm = (wave & 1) * 64;             // M: 2 x 64
  const int wn = (wave >> 1) * 32;            // N: 4 x 32

  const int srow = lane >> 3;                 // 0..7 row within 8-row group
  const int scol = ((lane & 7) ^ srow) * 8;   // xor-swizzled source column
  const int sw = l15 & 7;

  f32x4 acc[4][2];
#pragma unroll
  for (int i = 0; i < 4; i++)
#pragma unroll
    for (int j = 0; j < 2; j++) acc[i][j] = (f32x4){0.f, 0.f, 0.f, 0.f};

  // prologue: stage kb=0 into buffer 0 (2 A-groups + 2 B-groups per thread)
#pragma unroll
  for (int j = 0; j < 2; j++) {
    const int g = wave * 2 + j;               // 0..15 (8 rows each)
    glds16(A + (size_t)(mb + g * 8 + srow) * 1024 + scol, &As[0][g * 512 + lane * 8]);
    glds16(B + (size_t)(nb + g * 8 + srow) * 1024 + scol, &Bs[0][g * 512 + lane * 8]);
  }

  for (int it = 0; it < 16; ++it) {
    drain_then_sync();  // my buf[it] fills landed; all waves' buf[it^1] reads retired
    if (it < 15) {
      const int kb = (it + 1) * 64, bf_ = (it + 1) & 1;
#pragma unroll
      for (int j = 0; j < 2; j++) {
        const int g = wave * 2 + j;
        glds16(A + (size_t)(mb + g * 8 + srow) * 1024 + kb + scol, &As[bf_][g * 512 + lane * 8]);
        glds16(B + (size_t)(nb + g * 8 + srow) * 1024 + kb + scol, &Bs[bf_][g * 512 + lane * 8]);
      }
    }
    const u16* as = As[it & 1];
    const u16* bs = Bs[it & 1];
#pragma unroll
    for (int kk = 0; kk < 2; kk++) {
      const int cb = kk * 4;
      short8 af[4], bfr[2];
#pragma unroll
      for (int mi = 0; mi < 4; mi++)
        af[mi] = *(const short8*)&as[(wm + mi * 16 + l15) * 64 + ((cb + quad) ^ sw) * 8];
#pragma unroll
      for (int ni = 0; ni < 2; ni++)
        bfr[ni] = *(const short8*)&bs[(wn + ni * 16 + l15) * 64 + ((cb + quad) ^ sw) * 8];
#pragma unroll
      for (int mi = 0; mi < 4; mi++)
#pragma unroll
        for (int ni = 0; ni < 2; ni++)
          acc[mi][ni] = __builtin_amdgcn_mfma_f32_16x16x32_bf16(
              af[mi], bfr[ni], acc[mi][ni], 0, 0, 0);
    }
  }

  // epilogue: C/D layout col=l15, row=quad*4+r (r2-verified)
#pragma unroll
  for (int mi = 0; mi < 4; mi++)
#pragma unroll
    for (int r = 0; r < 4; r++) {
      const int row = mb + wm + mi * 16 + quad * 4 + r;
      const size_t base = (size_t)row * 1024 + nb + wn;
#pragma unroll
      for (int ni = 0; ni < 2; ni++)
        C[base + ni * 16 + l15] = f2bf(acc[mi][ni][r]);
    }
}

// ---- fused QK^T + columnwise LSE, atomicAdd combine over a ----
// r9's lse2 shape (4 k-tiles/wave, 56 VGPRs — no spill) with two changes:
// 128-row Q tiles (4 barriers/block instead of 8; prefetch covered by ~2x
// compute) and z4-as-C (no per-qt accumulator zeroing). NO launch-bounds
// min-waves arg (r10 lesson: it caps VGPRs = spill catastrophe).
__global__ __launch_bounds__(256) void attn_lse5(const u16* __restrict__ Qp,
                                                 const u16* __restrict__ Kp,
                                                 float* __restrict__ out) {
  __shared__ u16 qs[2][128 * 64];   // 32 KB double-buffered
  const int t = threadIdx.x;
  const int lane = t & 63, wave = t >> 6;
  const int l15 = lane & 15, quad = lane >> 4;
  const int kt = blockIdx.x & 1, aa = blockIdx.x >> 1;
  const int h = blockIdx.y, b = blockIdx.z;
  const int kwave = kt * 256 + wave * 64;

  // K fragments for 4 k-tiles x (d-lo, d-hi), in registers throughout
  short8 klo[4], khi[4];
#pragma unroll
  for (int tt = 0; tt < 4; tt++) {
    const short8* kg = (const short8*)(Kp + (size_t)(b * 512 + kwave + tt * 16 + l15) * 1024
                                       + h * 64 + quad * 8);
    klo[tt] = kg[0];
    khi[tt] = kg[4];   // +32 elements
  }

  const int srow = lane >> 3;
  const int scol = ((lane & 7) ^ srow) * 8;
  const u16* qbase = Qp + (size_t)(aa * 512) * 1024 + h * 64;

  // loop-invariant swizzled LDS read columns (in u16 elements)
  const int sw = l15 & 7;
  const int colLo = (quad ^ sw) * 8;
  const int colHi = ((4 + quad) ^ sw) * 8;
  const int rrow = l15 * 64;

  const f32x4 z4 = (f32x4){0.f, 0.f, 0.f, 0.f};   // persistent zero C operand
  float cs0 = 0.f, cs1 = 0.f, cs2 = 0.f, cs3 = 0.f;

  // prologue: stage tile 0 (128 q-rows = 16 groups of 8 rows, 4 per wave)
#pragma unroll
  for (int j = 0; j < 4; j++) {
    const int g = wave * 4 + j;
    glds16(qbase + (size_t)(g * 8 + srow) * 1024 + scol, &qs[0][g * 512 + lane * 8]);
  }

  for (int i = 0; i < 4; i++) {
    drain_then_sync();   // my tile-i fills landed; all tile-(i-1) reads retired
    if (i < 3) {
#pragma unroll
      for (int j = 0; j < 4; j++) {
        const int g = wave * 4 + j;
        glds16(qbase + (size_t)((i + 1) * 128 + g * 8 + srow) * 1024 + scol,
               &qs[(i + 1) & 1][g * 512 + lane * 8]);
      }
    }
    const u16* buf = qs[i & 1];
#pragma unroll
    for (int qt = 0; qt < 8; qt++) {
      short8 alo = *(const short8*)&buf[qt * 1024 + rrow + colLo];
      short8 ahi = *(const short8*)&buf[qt * 1024 + rrow + colHi];
      f32x4 a0 = __builtin_amdgcn_mfma_f32_16x16x32_bf16(
          ahi, khi[0], __builtin_amdgcn_mfma_f32_16x16x32_bf16(alo, klo[0], z4, 0, 0, 0), 0, 0, 0);
      f32x4 a1 = __builtin_amdgcn_mfma_f32_16x16x32_bf16(
          ahi, khi[1], __builtin_amdgcn_mfma_f32_16x16x32_bf16(alo, klo[1], z4, 0, 0, 0), 0, 0, 0);
      f32x4 a2 = __builtin_amdgcn_mfma_f32_16x16x32_bf16(
          ahi, khi[2], __builtin_amdgcn_mfma_f32_16x16x32_bf16(alo, klo[2], z4, 0, 0, 0), 0, 0, 0);
      f32x4 a3 = __builtin_amdgcn_mfma_f32_16x16x32_bf16(
          ahi, khi[3], __builtin_amdgcn_mfma_f32_16x16x32_bf16(alo, klo[3], z4, 0, 0, 0), 0, 0, 0);
#pragma unroll
      for (int r = 0; r < 4; r++) {
        cs0 += __builtin_amdgcn_exp2f(a0[r]);   // bare v_exp_f32
        cs1 += __builtin_amdgcn_exp2f(a1[r]);
        cs2 += __builtin_amdgcn_exp2f(a2[r]);
        cs3 += __builtin_amdgcn_exp2f(a3[r]);
      }
    }
  }
  // finish column sums over the 4 quads
  cs0 += __shfl_xor(cs0, 16); cs0 += __shfl_xor(cs0, 32);
  cs1 += __shfl_xor(cs1, 16); cs1 += __shfl_xor(cs1, 32);
  cs2 += __shfl_xor(cs2, 16); cs2 += __shfl_xor(cs2, 32);
  cs3 += __shfl_xor(cs3, 16); cs3 += __shfl_xor(cs3, 32);
  const float v = quad == 0 ? cs0 : quad == 1 ? cs1 : quad == 2 ? cs2 : cs3;
  atomicAdd(out + (size_t)b * 8192 + h * 512 + kwave + quad * 16 + l15, __logf(v));
}

extern "C" void kernel_launch(void* const* d_in, const int* in_sizes, int n_in,
                              void* d_out, int out_size, void* d_ws, size_t ws_size,
                              hipStream_t stream) {
  const float* query  = (const float*)d_in[0];  // [8,512,1024]
  const float* memory = (const float*)d_in[1];  // [8,512,1024]
  const float* wq     = (const float*)d_in[2];  // [1024,1024]
  const float* wk     = (const float*)d_in[3];  // [1024,1024]
  float* out = (float*)d_out;                   // [8,16,512]

  char* ws = (char*)d_ws;
  const size_t MB = 1024 * 1024;
  u16* qb  = (u16*)(ws);             // 8 MB bf16 query
  u16* mb_ = (u16*)(ws + 8  * MB);   // 8 MB bf16 memory
  u16* wqb = (u16*)(ws + 16 * MB);   // 2 MB bf16 W_Q * c
  u16* wkb = (u16*)(ws + 18 * MB);   // 2 MB bf16 W_K
  u16* Qp  = (u16*)(ws + 20 * MB);   // 8 MB projected Q'
  u16* Kp  = (u16*)(ws + 28 * MB);   // 8 MB projected K

  prep<<<10304, 256, 0, stream>>>((const float4*)query, (const float4*)memory,
                                  (const float4*)wq, (const float4*)wk,
                                  (ushort4*)qb, (ushort4*)mb_, (ushort4*)wqb,
                                  (ushort4*)wkb, (float4*)d_out);
  gemm_db<<<dim3(64, 8), 512, 0, stream>>>(qb, wqb, Qp, mb_, wkb, Kp);
  attn_lse5<<<dim3(16, 16, 8), 256, 0, stream>>>(Qp, Kp, out);
}